// Round 4
// baseline (256.660 us; speedup 1.0000x reference)
//
#include <hip/hip_runtime.h>
#include <hip/hip_bf16.h>

typedef __attribute__((ext_vector_type(8))) short bf16x8;
typedef __attribute__((ext_vector_type(4))) float f32x4;

#define C_    1024
#define MROWS 32768   // B*T*QH
#define D_    256     // per-head dim
#define S_TOT 4096
#define SCH   64      // S-chunk
#define NCH   (S_TOT / SCH)   // 64 chunks

__device__ __forceinline__ unsigned short f2bf(float f) {
  union { float f; unsigned int u; } v; v.f = f;
  unsigned int u = v.u;
  u += 0x7fffu + ((u >> 16) & 1u);   // round-to-nearest-even
  return (unsigned short)(u >> 16);
}

__device__ __forceinline__ void async16(const void* g, void* l) {
  __builtin_amdgcn_global_load_lds(
      (const __attribute__((address_space(1))) unsigned int*)g,
      (__attribute__((address_space(3))) unsigned int*)l, 16, 0, 0);
}

// ---------------- fused prep: LN + K-swizzle + V-swizzle -------------------
// blocks [0,2048): ln (4 rows each)
// blocks [2048,2560): prep_k
// blocks [2560,2688): prep_v
__global__ __launch_bounds__(256) void prep_all(
    const float* __restrict__ res, const float* __restrict__ g,
    const float* __restrict__ b, const float* __restrict__ wfc,
    const float* __restrict__ wproj,
    unsigned short* __restrict__ xq, unsigned short* __restrict__ kq,
    unsigned short* __restrict__ vq) {
  __shared__ unsigned short tile[8192];
  int bid = blockIdx.x;
  int tid = threadIdx.x;

  if (bid < 2048) {
    // -------- LayerNorm -> bf16 (one wave per row) --------
    int wave = tid >> 6, lane = tid & 63;
    int row = bid * 4 + wave;
    const float* r = res + (size_t)row * C_;
    float4 x[4];
    float s = 0.f, s2 = 0.f;
    #pragma unroll
    for (int i = 0; i < 4; ++i) {
      x[i] = *(const float4*)(r + i * 256 + lane * 4);
      s  += x[i].x + x[i].y + x[i].z + x[i].w;
      s2 += x[i].x * x[i].x + x[i].y * x[i].y + x[i].z * x[i].z + x[i].w * x[i].w;
    }
    #pragma unroll
    for (int off = 32; off > 0; off >>= 1) {
      s  += __shfl_xor(s, off, 64);
      s2 += __shfl_xor(s2, off, 64);
    }
    float mu  = s * (1.0f / C_);
    float var = s2 * (1.0f / C_) - mu * mu;
    float rs  = rsqrtf(var + 1e-5f);
    #pragma unroll
    for (int i = 0; i < 4; ++i) {
      int c = i * 256 + lane * 4;
      float4 gg = *(const float4*)(g + c);
      float4 bb = *(const float4*)(b + c);
      unsigned short o[4];
      o[0] = f2bf((x[i].x - mu) * rs * gg.x + bb.x);
      o[1] = f2bf((x[i].y - mu) * rs * gg.y + bb.y);
      o[2] = f2bf((x[i].z - mu) * rs * gg.z + bb.z);
      o[3] = f2bf((x[i].w - mu) * rs * gg.w + bb.w);
      *(ushort4*)(xq + (size_t)row * C_ + c) = *(ushort4*)o;
    }
  } else if (bid < 2560) {
    // -------- K -> bf16, MFMA B-fragment order --------
    // kq[((sc2*8+kc)*2+sn)*64+lane][j] = K[sc2*32+sn*16+(lane&15)][kc*32+(lane>>4)*8+j]
    int t = (bid - 2048) * 256 + tid;
    int lane = t & 63;
    int sn  = (t >> 6) & 1;
    int kc  = (t >> 7) & 7;
    int sc2 = t >> 10;
    int s = sc2 * 32 + sn * 16 + (lane & 15);
    int d = kc * 32 + (lane >> 4) * 8;
    const float* src = wfc + (size_t)s * D_ + d;
    float4 a = *(const float4*)src;
    float4 b2 = *(const float4*)(src + 4);
    unsigned short o[8] = { f2bf(a.x), f2bf(a.y), f2bf(a.z), f2bf(a.w),
                            f2bf(b2.x), f2bf(b2.y), f2bf(b2.z), f2bf(b2.w) };
    *(uint4*)(kq + (size_t)t * 8) = *(uint4*)o;
  } else {
    // -------- V -> bf16, MFMA B-fragment order --------
    // vq[(sc2*16+dn)*64+lane][j] = V[sc2*32+(lane>>4)*8+j][dn*16+(lane&15)]
    // V[s][d] = w_proj[(s&3)*256+d][s>>2]
    int bb = bid - 2560;                     // sc2
    int c0 = bb * 8;
    #pragma unroll
    for (int it = 0; it < 4; ++it) {
      int row = it * 256 + tid;              // rows of w_proj
      const float* src = wproj + (size_t)row * C_ + c0;
      float4 a = *(const float4*)src;
      float4 b2 = *(const float4*)(src + 4);
      unsigned short* dst = &tile[row * 8];
      dst[0] = f2bf(a.x);  dst[1] = f2bf(a.y);  dst[2] = f2bf(a.z);  dst[3] = f2bf(a.w);
      dst[4] = f2bf(b2.x); dst[5] = f2bf(b2.y); dst[6] = f2bf(b2.z); dst[7] = f2bf(b2.w);
    }
    __syncthreads();
    #pragma unroll
    for (int it = 0; it < 4; ++it) {
      int slot = it * 256 + tid;             // dn*64 + lane
      int lane = slot & 63;
      int dn   = slot >> 6;
      int d = dn * 16 + (lane & 15);
      int sl0 = (lane >> 4) * 8;
      unsigned short o[8];
      #pragma unroll
      for (int j = 0; j < 8; ++j) {
        int sl = sl0 + j;
        o[j] = tile[((sl & 3) * 256 + d) * 8 + (sl >> 2)];
      }
      *(uint4*)(vq + (size_t)bb * 8192 + (size_t)slot * 8) = *(uint4*)o;
    }
  }
}

// ------- fused main: 8 waves, SCH=64, scores 2Mx4S (Q-reg), PV 4Nx2M -------
__global__ __launch_bounds__(512, 2) void mlpmha_main(
    const unsigned short* __restrict__ xq,
    const unsigned short* __restrict__ kq,
    const unsigned short* __restrict__ vq,
    const float* __restrict__ res,
    float* __restrict__ out) {
  __shared__ unsigned short ldsK[2][16384];   // 32KB x2, fragment-linear
  __shared__ unsigned short ldsV[16384];      // 32KB, fragment-linear
  __shared__ unsigned short ldsP[2][128][36]; // two 32-s halves, +4 pad

  int tid  = threadIdx.x;
  int wave = tid >> 6;
  int lane = tid & 63;
  int l16  = lane & 15;
  int quad = lane >> 4;
  int wgM  = blockIdx.x * 128;

  // scores: wave = (mi, si) -> 64 rows x 16 s-cols
  int mi = wave & 1, si = wave >> 1;
  int sh = si >> 1, sl = si & 1;
  // PV: wave = (ni, mi2) -> 64 cols x 64 rows
  int ni = wave & 3, mi2 = wave >> 2;

  // Q fragments: 4 m-tiles x 8 k-chunks, register resident (128 VGPRs)
  bf16x8 qf[4][8];
  #pragma unroll
  for (int mt = 0; mt < 4; ++mt) {
    const unsigned short* qr =
        xq + (size_t)(wgM + mi * 64 + mt * 16 + l16) * D_ + quad * 8;
    #pragma unroll
    for (int kc = 0; kc < 8; ++kc) qf[mt][kc] = *(const bf16x8*)(qr + kc * 32);
  }

  f32x4 acc[4][4];   // [mt2][dnl]
  #pragma unroll
  for (int i = 0; i < 4; ++i)
    #pragma unroll
    for (int j = 0; j < 4; ++j) acc[i][j] = (f32x4){0.f, 0.f, 0.f, 0.f};

  int soff = tid * 8;   // staging offset in shorts (= tid*16 B)

  // prologue: K chunk 0 -> buf 0 (32 KB)
  {
    const unsigned short* kg = kq + soff;
    #pragma unroll
    for (int i = 0; i < 4; ++i)
      async16(kg + i * 4096, &ldsK[0][soff + i * 4096]);
  }
  __syncthreads();

  for (int sc = 0; sc < NCH; ++sc) {
    int cur = sc & 1;

    // prefetch V(sc) during scores (ldsV free: prev PV done at chunk-end barrier)
    {
      const unsigned short* vg = vq + (size_t)sc * 16384 + soff;
      #pragma unroll
      for (int i = 0; i < 4; ++i)
        async16(vg + i * 4096, &ldsV[soff + i * 4096]);
    }

    // ---- scores: 64 rows x 16 s-cols per wave, K=256
    f32x4 sacc[4];
    #pragma unroll
    for (int mt = 0; mt < 4; ++mt) sacc[mt] = (f32x4){0.f, 0.f, 0.f, 0.f};
    #pragma unroll
    for (int kc = 0; kc < 8; ++kc) {
      bf16x8 kb = *(const bf16x8*)&ldsK[cur][sh * 8192 + (kc * 2 + sl) * 512 + lane * 8];
      #pragma unroll
      for (int mt = 0; mt < 4; ++mt)
        sacc[mt] = __builtin_amdgcn_mfma_f32_16x16x32_bf16(qf[mt][kc], kb, sacc[mt], 0, 0, 0);
    }

    // ---- P = relu(score)^2 -> shared LDS (half sh, cols sl*16+l16)
    #pragma unroll
    for (int mt = 0; mt < 4; ++mt)
      #pragma unroll
      for (int r = 0; r < 4; ++r) {
        float v = sacc[mt][r];
        v = v > 0.f ? v * v : 0.f;
        ldsP[sh][mi * 64 + mt * 16 + quad * 4 + r][sl * 16 + l16] = f2bf(v);
      }

    __syncthreads();   // P visible; V(sc) drained

    // prefetch K(sc+1) during PV
    if (sc + 1 < NCH) {
      const unsigned short* kg = kq + (size_t)(sc + 1) * 16384 + soff;
      #pragma unroll
      for (int i = 0; i < 4; ++i)
        async16(kg + i * 4096, &ldsK[1 - cur][soff + i * 4096]);
    }

    // ---- PV: 64 rows x 64 cols per wave, K = 64 (two 32-s halves)
    #pragma unroll
    for (int h = 0; h < 2; ++h) {
      bf16x8 vb[4];
      #pragma unroll
      for (int dnl = 0; dnl < 4; ++dnl)
        vb[dnl] = *(const bf16x8*)&ldsV[h * 8192 + ((ni * 4 + dnl) * 64 + lane) * 8];
      #pragma unroll
      for (int mt2 = 0; mt2 < 4; ++mt2) {
        const unsigned short* pp = &ldsP[h][mi2 * 64 + mt2 * 16 + l16][quad * 8];
        union { ushort4 u4[2]; bf16x8 v; } pu;
        pu.u4[0] = *(const ushort4*)pp;
        pu.u4[1] = *(const ushort4*)(pp + 4);
        bf16x8 pa = pu.v;
        #pragma unroll
        for (int dnl = 0; dnl < 4; ++dnl)
          acc[mt2][dnl] = __builtin_amdgcn_mfma_f32_16x16x32_bf16(pa, vb[dnl], acc[mt2][dnl], 0, 0, 0);
      }
    }

    __syncthreads();   // P/V reusable; K(sc+1) drained
  }

  // ---- epilogue: out = residual + acc
  #pragma unroll
  for (int mt2 = 0; mt2 < 4; ++mt2)
    #pragma unroll
    for (int r = 0; r < 4; ++r) {
      size_t row = (size_t)(wgM + mi2 * 64 + mt2 * 16 + quad * 4 + r) * D_;
      #pragma unroll
      for (int dnl = 0; dnl < 4; ++dnl) {
        size_t idx = row + ni * 64 + dnl * 16 + l16;
        out[idx] = res[idx] + acc[mt2][dnl][r];
      }
    }
}

extern "C" void kernel_launch(void* const* d_in, const int* in_sizes, int n_in,
                              void* d_out, int out_size, void* d_ws, size_t ws_size,
                              hipStream_t stream) {
  const float* res   = (const float*)d_in[0];
  const float* wfc   = (const float*)d_in[1];
  const float* wproj = (const float*)d_in[2];
  const float* g     = (const float*)d_in[3];
  const float* b     = (const float*)d_in[4];
  float* out = (float*)d_out;

  unsigned short* xq = (unsigned short*)d_ws;              // 32768*256 bf16 = 16 MB
  unsigned short* kq = xq + (size_t)MROWS * D_;            // 4096*256 bf16  =  2 MB
  unsigned short* vq = kq + (size_t)S_TOT * D_;            // 4096*256 bf16  =  2 MB

  prep_all<<<2688, 256, 0, stream>>>(res, g, b, wfc, wproj, xq, kq, vq);
  mlpmha_main<<<256, 512, 0, stream>>>(xq, kq, vq, res, out);
}